// Round 12
// baseline (42.391 us; speedup 1.0000x reference)
//
#include <hip/hip_runtime.h>
#include <math.h>

#define NBLOCKS 1280
#define NTHREADS 256
#define THREADS_TOTAL (NBLOCKS * NTHREADS)   // 327,680
#define ITERS 15                              // 327,680 * 15 = 4,915,200 quads

// image geometry (fixed by the reference): W=640, H=480
#define ROW4 160
#define IMG4 76800
// per-iteration stride within an image: THREADS_TOTAL mod IMG4 = 20480 = exactly 128 rows
#define H_STEP 128

// constants from the reference
#define K_CX 313.0447587080473f
#define K_CY 238.44389626620386f
#define K_RFX (1.0f / 582.6244816773795f)
#define K_RFY (1.0f / 582.6910327098864f)
#define LN2_SQ 0.48045301391820142467f   // (ln 2)^2

typedef float f32x4 __attribute__((ext_vector_type(4)));

// ---------------------------------------------------------------------------
// Fused epilogue WITHOUT __threadfence (R8: fence -> per-block buffer_wbl2 L2
// scan, 2x kernel time). Instead: agent-scope (sc1) atomic stores write the
// partials through to LLC; one vmcnt drain; relaxed agent-scope RMW on the
// counter (LLC-serialized). Last block reads partials with agent-scope loads
// (sc1 -> fetch from LLC, bypass possibly-stale local L1/L2).
__device__ __forceinline__ void block_reduce_finalize(
        float cnt, float sx, float sy, float sz, float sl,
        double* __restrict__ partial, unsigned* __restrict__ counter,
        int nb, int bid, float* __restrict__ out) {
#pragma unroll
    for (int o = 32; o > 0; o >>= 1) {
        cnt += __shfl_down(cnt, o);
        sx  += __shfl_down(sx, o);
        sy  += __shfl_down(sy, o);
        sz  += __shfl_down(sz, o);
        sl  += __shfl_down(sl, o);
    }
    __shared__ float part[4][5];
    __shared__ int lastFlag;
    int wave = threadIdx.x >> 6;
    int lane = threadIdx.x & 63;
    if (lane == 0) {
        part[wave][0] = cnt; part[wave][1] = sx; part[wave][2] = sy;
        part[wave][3] = sz;  part[wave][4] = sl;
    }
    __syncthreads();
    if (threadIdx.x == 0) {
        double t[5] = {0, 0, 0, 0, 0};
#pragma unroll
        for (int w = 0; w < 4; ++w)
#pragma unroll
            for (int j = 0; j < 5; ++j) t[j] += (double)part[w][j];
        // device-coherent stores (sc1): visible at LLC, no L2 writeback scan
#pragma unroll
        for (int j = 0; j < 5; ++j)
            __hip_atomic_store(&partial[j * nb + bid], t[j],
                               __ATOMIC_RELAXED, __HIP_MEMORY_SCOPE_AGENT);
        // drain the stores to LLC before signaling arrival
        asm volatile("s_waitcnt vmcnt(0)" ::: "memory");
        unsigned old = __hip_atomic_fetch_add(counter, 1u,
                               __ATOMIC_RELAXED, __HIP_MEMORY_SCOPE_AGENT);
        lastFlag = (old == (unsigned)(nb - 1));
    }
    __syncthreads();
    if (!lastFlag) return;

    // last block: all partials are at LLC (their stores drained before their
    // counter increments, which serialize at LLC). Read with agent-scope loads.
    double s[5] = {0, 0, 0, 0, 0};
    for (int i = threadIdx.x; i < nb; i += NTHREADS)
#pragma unroll
        for (int j = 0; j < 5; ++j)
            s[j] += __hip_atomic_load(&partial[j * nb + i],
                                      __ATOMIC_RELAXED, __HIP_MEMORY_SCOPE_AGENT);
#pragma unroll
    for (int o = 32; o > 0; o >>= 1)
#pragma unroll
        for (int j = 0; j < 5; ++j) s[j] += __shfl_down(s[j], o);

    __shared__ double dpart[4][5];
    if (lane == 0)
#pragma unroll
        for (int j = 0; j < 5; ++j) dpart[wave][j] = s[j];
    __syncthreads();
    if (threadIdx.x == 0) {
#pragma unroll
        for (int w = 1; w < 4; ++w)
#pragma unroll
            for (int j = 0; j < 5; ++j) dpart[0][j] += dpart[w][j];
        double n  = dpart[0][0];
        double lx = sqrt(dpart[0][1] / n);
        double ly = sqrt(dpart[0][2] / n);
        double lz = sqrt(dpart[0][3] / n);
        double ll = sqrt(dpart[0][4] / n);
        double loss = 10.0 * (ll + fabs(10.0 * (3.0 - exp(lx) - exp(ly) - exp(lz))));
        out[0] = (float)loss;
    }
}

// ---------------------------------------------------------------------------
// fast path: identical loads/loop to R11 (nt loads, no in-loop divs, a^2
// factored out); only the epilogue changed.
__global__ __launch_bounds__(NTHREADS) void ddd_reduce15_kernel(
        const f32x4* __restrict__ fake, const f32x4* __restrict__ real,
        double* __restrict__ partial, unsigned* __restrict__ counter,
        float* __restrict__ out) {
    const int tid  = blockIdx.x * NTHREADS + threadIdx.x;
    const int pos  = tid % IMG4;          // once per thread
    const int col4 = (pos % ROW4) * 4;
    int h          = pos / ROW4;

    float a2v[4];
#pragma unroll
    for (int j = 0; j < 4; ++j) {
        float a = ((float)(col4 + j) - K_CX) * K_RFX;
        a2v[j] = a * a;
    }

    // issue all loads back-to-back, non-temporal (streaming read-once)
    f32x4 fb[ITERS], rb[ITERS];
#pragma unroll
    for (int k = 0; k < ITERS; ++k) {
        fb[k] = __builtin_nontemporal_load(fake + tid + k * THREADS_TOTAL);
        rb[k] = __builtin_nontemporal_load(real + tid + k * THREADS_TOTAL);
    }

    float cnt = 0.f, sy = 0.f, sl2 = 0.f;
    float sd2[4] = {0.f, 0.f, 0.f, 0.f};
#pragma unroll
    for (int k = 0; k < ITERS; ++k) {
        float b = ((float)h - K_CY) * K_RFY;
        h += H_STEP; if (h >= 480) h -= 480;
#pragma unroll
        for (int j = 0; j < 4; ++j) {
            float fj = fb[k][j], rj = rb[k][j];
            bool m = (rj > 0.f) & (rj < 1.f) & (fj > 0.f) & (fj < 1.f);
            // inside the mask r,f in (0,1), a,b != 0 -> eps replacements are no-ops
            float d  = rj - fj;
            float dl = __log2f(rj) - __log2f(fj);
            d  = m ? d  : 0.f;
            dl = m ? dl : 0.f;
            float db = d * b;
            sd2[j] += d * d;
            sy     += db * db;
            sl2    += dl * dl;
            cnt    += m ? 1.f : 0.f;
        }
    }

    float sz = sd2[0] + sd2[1] + sd2[2] + sd2[3];
    float sx = a2v[0]*sd2[0] + a2v[1]*sd2[1] + a2v[2]*sd2[2] + a2v[3]*sd2[3];

    block_reduce_finalize(cnt, sx, sy, sz, sl2 * LN2_SQ,
                          partial, counter, NBLOCKS, blockIdx.x, out);
}

// generic fallback: any total4 (grid-stride, in-loop divs, plain loads)
__global__ __launch_bounds__(NTHREADS) void ddd_reduce_gen_kernel(
        const float4* __restrict__ fake, const float4* __restrict__ real,
        double* __restrict__ partial, unsigned* __restrict__ counter,
        float* __restrict__ out, int total4) {
    float cnt = 0.f, sx = 0.f, sy = 0.f, sz = 0.f, sl2 = 0.f;
    for (int i = blockIdx.x * NTHREADS + threadIdx.x; i < total4; i += THREADS_TOTAL) {
        float4 f = fake[i];
        float4 r = real[i];
        int pos  = i % IMG4;
        int col4 = (pos % ROW4) * 4;
        int hh   = pos / ROW4;
        float b  = ((float)hh - K_CY) * K_RFY;
        float fv[4] = {f.x, f.y, f.z, f.w};
        float rv[4] = {r.x, r.y, r.z, r.w};
#pragma unroll
        for (int j = 0; j < 4; ++j) {
            float fj = fv[j], rj = rv[j];
            bool m = (rj > 0.f) & (rj < 1.f) & (fj > 0.f) & (fj < 1.f);
            float a  = ((float)(col4 + j) - K_CX) * K_RFX;
            float d  = rj - fj;
            float dl = __log2f(rj) - __log2f(fj);
            d  = m ? d  : 0.f;
            dl = m ? dl : 0.f;
            float da = d * a, db = d * b;
            sx  += da * da;
            sy  += db * db;
            sz  += d * d;
            sl2 += dl * dl;
            cnt += m ? 1.f : 0.f;
        }
    }
    block_reduce_finalize(cnt, sx, sy, sz, sl2 * LN2_SQ,
                          partial, counter, NBLOCKS, blockIdx.x, out);
}

// ---------------------------------------------------------------------------
extern "C" void kernel_launch(void* const* d_in, const int* in_sizes, int n_in,
                              void* d_out, int out_size, void* d_ws, size_t ws_size,
                              hipStream_t stream) {
    const float4* fake = (const float4*)d_in[0];
    const float4* real = (const float4*)d_in[1];
    float* out = (float*)d_out;
    double* partial = (double*)d_ws;                       // 5*NBLOCKS*8 = 51,200 B
    unsigned* counter = (unsigned*)((char*)d_ws + 5 * NBLOCKS * sizeof(double));

    int total  = in_sizes[0];
    int total4 = total / 4;

    hipMemsetAsync(counter, 0, sizeof(unsigned), stream);  // graph-legal memset node
    if (total4 == ITERS * THREADS_TOTAL) {
        ddd_reduce15_kernel<<<NBLOCKS, NTHREADS, 0, stream>>>(
            (const f32x4*)fake, (const f32x4*)real, partial, counter, out);
    } else {
        ddd_reduce_gen_kernel<<<NBLOCKS, NTHREADS, 0, stream>>>(
            fake, real, partial, counter, out, total4);
    }
}

// Round 13
// 33.647 us; speedup vs baseline: 1.2599x; 1.2599x over previous
//
#include <hip/hip_runtime.h>
#include <math.h>

#define NBLOCKS 1280
#define NTHREADS 256
#define THREADS_TOTAL (NBLOCKS * NTHREADS)   // 327,680
#define ITERS 15                              // 327,680 * 15 = 4,915,200 quads

// image geometry (fixed by the reference): W=640, H=480
#define ROW4 160
#define IMG4 76800
// per-iteration stride within an image: THREADS_TOTAL mod IMG4 = 20480 = exactly 128 rows
#define H_STEP 128

// constants from the reference
#define K_CX 313.0447587080473f
#define K_CY 238.44389626620386f
#define K_RFX (1.0f / 582.6244816773795f)
#define K_RFY (1.0f / 582.6910327098864f)
#define LN2_SQ 0.48045301391820142467f   // (ln 2)^2

typedef float f32x4 __attribute__((ext_vector_type(4)));

// ---------------------------------------------------------------------------
// wave + block reduce, then store 5 partials for this block (SoA, no atomics).
// No __threadfence (R8: per-block device-scope fence -> buffer_wbl2 storm, 2x).
// No agent-scope sc1 epilogue either (R12: also a regression). Kernel boundary
// provides cross-XCD coherence for free.
__device__ __forceinline__ void block_reduce_store(
        float cnt, float sx, float sy, float sz, float sl,
        double* __restrict__ partial, int nb, int bid) {
#pragma unroll
    for (int o = 32; o > 0; o >>= 1) {
        cnt += __shfl_down(cnt, o);
        sx  += __shfl_down(sx, o);
        sy  += __shfl_down(sy, o);
        sz  += __shfl_down(sz, o);
        sl  += __shfl_down(sl, o);
    }
    __shared__ float part[4][5];
    int wave = threadIdx.x >> 6;
    int lane = threadIdx.x & 63;
    if (lane == 0) {
        part[wave][0] = cnt; part[wave][1] = sx; part[wave][2] = sy;
        part[wave][3] = sz;  part[wave][4] = sl;
    }
    __syncthreads();
    if (threadIdx.x == 0) {
        double t[5] = {0, 0, 0, 0, 0};
#pragma unroll
        for (int w = 0; w < 4; ++w)
#pragma unroll
            for (int j = 0; j < 5; ++j) t[j] += (double)part[w][j];
#pragma unroll
        for (int j = 0; j < 5; ++j) partial[j * nb + bid] = t[j];
    }
}

// ---------------------------------------------------------------------------
// fast path: nt loads (streaming read-once), no in-loop divs, a^2 factored out.
__global__ __launch_bounds__(NTHREADS) void ddd_reduce15_kernel(
        const f32x4* __restrict__ fake, const f32x4* __restrict__ real,
        double* __restrict__ partial) {
    const int tid  = blockIdx.x * NTHREADS + threadIdx.x;
    const int pos  = tid % IMG4;          // once per thread
    const int col4 = (pos % ROW4) * 4;
    int h          = pos / ROW4;

    float a2v[4];
#pragma unroll
    for (int j = 0; j < 4; ++j) {
        float a = ((float)(col4 + j) - K_CX) * K_RFX;
        a2v[j] = a * a;
    }

    // issue all loads back-to-back, interleaved (compiler batches ~8 deep)
    f32x4 fb[ITERS], rb[ITERS];
#pragma unroll
    for (int k = 0; k < ITERS; ++k) {
        fb[k] = __builtin_nontemporal_load(fake + tid + k * THREADS_TOTAL);
        rb[k] = __builtin_nontemporal_load(real + tid + k * THREADS_TOTAL);
    }

    float cnt = 0.f, sy = 0.f, sl2 = 0.f;
    float sd2[4] = {0.f, 0.f, 0.f, 0.f};
#pragma unroll
    for (int k = 0; k < ITERS; ++k) {
        float b = ((float)h - K_CY) * K_RFY;
        h += H_STEP; if (h >= 480) h -= 480;
#pragma unroll
        for (int j = 0; j < 4; ++j) {
            float fj = fb[k][j], rj = rb[k][j];
            bool m = (rj > 0.f) & (rj < 1.f) & (fj > 0.f) & (fj < 1.f);
            // inside the mask r,f in (0,1), a,b != 0 -> eps replacements are no-ops
            float d  = rj - fj;
            float dl = __log2f(rj) - __log2f(fj);
            d  = m ? d  : 0.f;
            dl = m ? dl : 0.f;
            float db = d * b;
            sd2[j] += d * d;
            sy     += db * db;
            sl2    += dl * dl;
            cnt    += m ? 1.f : 0.f;
        }
    }

    float sz = sd2[0] + sd2[1] + sd2[2] + sd2[3];
    float sx = a2v[0]*sd2[0] + a2v[1]*sd2[1] + a2v[2]*sd2[2] + a2v[3]*sd2[3];

    block_reduce_store(cnt, sx, sy, sz, sl2 * LN2_SQ, partial, NBLOCKS, blockIdx.x);
}

// generic fallback: any total4 (grid-stride, in-loop divs, plain loads)
__global__ __launch_bounds__(NTHREADS) void ddd_reduce_gen_kernel(
        const float4* __restrict__ fake, const float4* __restrict__ real,
        double* __restrict__ partial, int total4) {
    float cnt = 0.f, sx = 0.f, sy = 0.f, sz = 0.f, sl2 = 0.f;
    for (int i = blockIdx.x * NTHREADS + threadIdx.x; i < total4; i += THREADS_TOTAL) {
        float4 f = fake[i];
        float4 r = real[i];
        int pos  = i % IMG4;
        int col4 = (pos % ROW4) * 4;
        int hh   = pos / ROW4;
        float b  = ((float)hh - K_CY) * K_RFY;
        float fv[4] = {f.x, f.y, f.z, f.w};
        float rv[4] = {r.x, r.y, r.z, r.w};
#pragma unroll
        for (int j = 0; j < 4; ++j) {
            float fj = fv[j], rj = rv[j];
            bool m = (rj > 0.f) & (rj < 1.f) & (fj > 0.f) & (fj < 1.f);
            float a  = ((float)(col4 + j) - K_CX) * K_RFX;
            float d  = rj - fj;
            float dl = __log2f(rj) - __log2f(fj);
            d  = m ? d  : 0.f;
            dl = m ? dl : 0.f;
            float da = d * a, db = d * b;
            sx  += da * da;
            sy  += db * db;
            sz  += d * d;
            sl2 += dl * dl;
            cnt += m ? 1.f : 0.f;
        }
    }
    block_reduce_store(cnt, sx, sy, sz, sl2 * LN2_SQ, partial, NBLOCKS, blockIdx.x);
}

// ---------------------------------------------------------------------------
// finalize: 256 threads sum nb partials per quantity (nb*5*8 = 51 KB read)
__global__ __launch_bounds__(NTHREADS) void finalize_kernel(
        const double* __restrict__ partial, int nb, float* __restrict__ out) {
    double t[5] = {0, 0, 0, 0, 0};
    for (int i = threadIdx.x; i < nb; i += NTHREADS)
#pragma unroll
        for (int j = 0; j < 5; ++j) t[j] += partial[j * nb + i];
#pragma unroll
    for (int o = 32; o > 0; o >>= 1)
#pragma unroll
        for (int j = 0; j < 5; ++j) t[j] += __shfl_down(t[j], o);

    __shared__ double part[4][5];
    int wave = threadIdx.x >> 6;
    int lane = threadIdx.x & 63;
    if (lane == 0)
#pragma unroll
        for (int j = 0; j < 5; ++j) part[wave][j] = t[j];
    __syncthreads();

    if (threadIdx.x == 0) {
#pragma unroll
        for (int w = 1; w < 4; ++w)
#pragma unroll
            for (int j = 0; j < 5; ++j) part[0][j] += part[w][j];
        double n  = part[0][0];
        double lx = sqrt(part[0][1] / n);
        double ly = sqrt(part[0][2] / n);
        double lz = sqrt(part[0][3] / n);
        double ll = sqrt(part[0][4] / n);
        double loss = 10.0 * (ll + fabs(10.0 * (3.0 - exp(lx) - exp(ly) - exp(lz))));
        out[0] = (float)loss;
    }
}

// ---------------------------------------------------------------------------
extern "C" void kernel_launch(void* const* d_in, const int* in_sizes, int n_in,
                              void* d_out, int out_size, void* d_ws, size_t ws_size,
                              hipStream_t stream) {
    const float4* fake = (const float4*)d_in[0];
    const float4* real = (const float4*)d_in[1];
    float* out = (float*)d_out;
    double* partial = (double*)d_ws;   // needs NBLOCKS*5*8 = 51,200 B of scratch

    int total  = in_sizes[0];
    int total4 = total / 4;

    if (total4 == ITERS * THREADS_TOTAL) {
        ddd_reduce15_kernel<<<NBLOCKS, NTHREADS, 0, stream>>>(
            (const f32x4*)fake, (const f32x4*)real, partial);
    } else {
        ddd_reduce_gen_kernel<<<NBLOCKS, NTHREADS, 0, stream>>>(fake, real, partial, total4);
    }
    finalize_kernel<<<1, NTHREADS, 0, stream>>>(partial, NBLOCKS, out);
}